// Round 6
// baseline (184.431 us; speedup 1.0000x reference)
//
#include <hip/hip_runtime.h>

// Problem constants
constexpr int Bb  = 16;
constexpr int CDD = 10;
constexpr int Lc  = 64;
constexpr int T   = 128;
constexpr int H   = 768;
constexpr int NH  = 12;
constexpr int DH  = 64;    // H/NH
constexpr int S   = 768;   // CDD*Lc + T
constexpr int SQ  = 640;   // CDD*Lc
constexpr int MROWS = Bb * S;  // 12288

typedef __attribute__((ext_vector_type(8))) short bf16x8;
typedef __attribute__((ext_vector_type(4))) short bf16x4;
typedef __attribute__((ext_vector_type(4))) float f32x4;

__device__ inline unsigned short f2bf(float f) {
  unsigned u = __float_as_uint(f);
  u += 0x7fff + ((u >> 16) & 1);   // RNE
  return (unsigned short)(u >> 16);
}
__device__ inline float bf2f(unsigned short h) {
  return __uint_as_float(((unsigned)h) << 16);
}

__device__ inline void gld_lds16(const void* g, void* l) {
  __builtin_amdgcn_global_load_lds(
      (const __attribute__((address_space(1))) void*)g,
      (__attribute__((address_space(3))) void*)l, 16, 0, 0);
}

__device__ inline bf16x8 ld_b64x2(const unsigned short* p) {
  union { bf16x8 v; bf16x4 h[2]; } u;
  u.h[0] = *(const bf16x4*)p;
  u.h[1] = *(const bf16x4*)(p + 4);
  return u.v;
}

// ---------------- fp32 -> bf16 convert (X + 3 weights, one launch) ------------
constexpr int NX4 = MROWS * H / 4;   // 2359296 float4s
constexpr int NW4 = H * H / 4;       // 147456 float4s
__global__ void convert_all(const float* __restrict__ X,
                            const float* __restrict__ Wq,
                            const float* __restrict__ Wk,
                            const float* __restrict__ Wv,
                            unsigned short* __restrict__ Xb,
                            unsigned short* __restrict__ Wb) {
  int i = blockIdx.x * blockDim.x + threadIdx.x;
  const int stride = gridDim.x * blockDim.x;
  const int total = NX4 + 3 * NW4;
  for (; i < total; i += stride) {
    const float* src;
    unsigned short* dst;
    int off;
    if (i < NX4) {
      src = X; dst = Xb; off = i;
    } else {
      int k = i - NX4;
      int w = k / NW4;
      off = k - w * NW4;
      src = (w == 0) ? Wq : (w == 1) ? Wk : Wv;
      dst = Wb + (size_t)w * H * H;
    }
    float4 v = ((const float4*)src)[off];
    ushort4 o;
    o.x = f2bf(v.x); o.y = f2bf(v.y); o.z = f2bf(v.z); o.w = f2bf(v.w);
    ((ushort4*)dst)[off] = o;
  }
}

// ---------------- QKV projection GEMM: Y = X * W^T + bias ----------------
// (r0 structure, proven 55 us / MfmaUtil ~30%. 128x128 tile, BK=64, 4 waves.
//  256-sq phase-interleave attempts regressed at this shape: K=768 gives only
//  12 K-tiles and 128KB LDS forces 1 block/CU -> pipeline never fills.)
// r6: z is a kernel argument; one dispatch per z so attn/convert surface in
// the profiler's top-5 (the three ~18us gemms sort below them).
// z=0 launches with grid (80,6): dense remap skipping the tail-only row tile
// (rows 640-767 of each batch are never consumed by attention as Q).
__launch_bounds__(256, 4)
__global__ void qkv_gemm(const unsigned short* __restrict__ Xb,
                         const unsigned short* __restrict__ Wb,
                         const int z,
                         const float* __restrict__ bq, const float* __restrict__ bk,
                         const float* __restrict__ bv,
                         unsigned short* __restrict__ Qb, unsigned short* __restrict__ Kb,
                         unsigned short* __restrict__ Vb,
                         float* __restrict__ part,
                         float* __restrict__ out) {
  const unsigned short* W = Wb + (size_t)z * H * H;
  const float* bias = (z == 0) ? bq : (z == 1) ? bk : bv;
  unsigned short* Y = (z == 0) ? Qb : (z == 1) ? Kb : Vb;

  const int bx = blockIdx.x;
  int i0;
  if (z == 0) {                     // grid.x=80: 16 batches x 5 live tiles
    const int b6 = bx / 5, t = bx - b6 * 5;
    i0 = (b6 * 6 + t) * 128;
  } else {
    i0 = bx * 128;
  }
  const int j0 = blockIdx.y * 128;
  const int tid = threadIdx.x;
  const int wave = tid >> 6, lane = tid & 63;
  const int wr = wave >> 1, wc = wave & 1;
  const int col = lane & 15, quad = lane >> 4;

  // row stride 64 elems (8 chunks of 8 bf16); chunk swizzle ^(row&7)
  __shared__ unsigned short As[128 * 64];
  __shared__ unsigned short Bs[128 * 64];

  f32x4 acc[4][4];
#pragma unroll
  for (int i = 0; i < 4; i++)
#pragma unroll
    for (int j = 0; j < 4; j++) acc[i][j] = (f32x4){0.f, 0.f, 0.f, 0.f};

  int rS[4], gcS[4];
#pragma unroll
  for (int i = 0; i < 4; i++) {
    int s = tid + 256 * i;
    rS[i] = s >> 3;
    gcS[i] = (s & 7) ^ (rS[i] & 7);
  }

  for (int kt = 0; kt < 12; kt++) {
    const int k0 = kt * 64;
#pragma unroll
    for (int i = 0; i < 4; i++)
      gld_lds16(Xb + (size_t)(i0 + rS[i]) * H + k0 + gcS[i] * 8, &As[(tid + 256 * i) * 8]);
#pragma unroll
    for (int i = 0; i < 4; i++)
      gld_lds16(W + (size_t)(j0 + rS[i]) * H + k0 + gcS[i] * 8, &Bs[(tid + 256 * i) * 8]);
    __builtin_amdgcn_s_waitcnt(0);
    __syncthreads();

#pragma unroll
    for (int h = 0; h < 2; h++) {
      bf16x8 a[4], b[4];
#pragma unroll
      for (int mt = 0; mt < 4; mt++) {
        int r = wr * 64 + mt * 16 + col;
        a[mt] = *(const bf16x8*)&As[r * 64 + (((h * 4 + quad) ^ (r & 7)) * 8)];
      }
#pragma unroll
      for (int nt = 0; nt < 4; nt++) {
        int r = wc * 64 + nt * 16 + col;
        b[nt] = *(const bf16x8*)&Bs[r * 64 + (((h * 4 + quad) ^ (r & 7)) * 8)];
      }
#pragma unroll
      for (int mt = 0; mt < 4; mt++)
#pragma unroll
        for (int nt = 0; nt < 4; nt++)
          acc[mt][nt] = __builtin_amdgcn_mfma_f32_16x16x32_bf16(a[mt], b[nt], acc[mt][nt], 0, 0, 0);
    }
    __syncthreads();
  }

  float colsum[4] = {0.f, 0.f, 0.f, 0.f};
#pragma unroll
  for (int mt = 0; mt < 4; mt++) {
#pragma unroll
    for (int nt = 0; nt < 4; nt++) {
      const int j = j0 + wc * 64 + nt * 16 + col;
      const float bj = bias[j];
#pragma unroll
      for (int r = 0; r < 4; r++) {
        const int i = i0 + wr * 64 + mt * 16 + quad * 4 + r;
        const float v = acc[mt][nt][r] + bj;
        Y[(size_t)i * H + j] = f2bf(v);
        if (z == 2) {
          colsum[nt] += v;
          int s = i - (i / S) * S;
          if (s >= SQ) out[(size_t)i * H + j] = v;  // tail rows: out = V row
        }
      }
    }
  }
  if (z == 2) {
    const int b = bx / 6;
#pragma unroll
    for (int nt = 0; nt < 4; nt++) {
      float s = colsum[nt];
      s += __shfl_xor(s, 16, 64);
      s += __shfl_xor(s, 32, 64);
      if (quad == 0) {
        const int j = j0 + wc * 64 + nt * 16 + col;
        atomicAdd(&part[b * H + j], s);
      }
    }
  }
}

// ---------------- fused masked attention ----------------
// One block per (b, h, chunk c). 192 live keys = chunk(64) + tail(128).
// Masked keys have score exactly 0 (multiplicative mask), closed form:
//   m = max(0, max live s);  Z = sum live e^(s-m) + 576 e^-m
//   ctx = (sum live e^(s-m) v + e^-m (Vtot - sum staged v)) / Z
// r6 changes vs r5:
//  (c) Q straight to registers: each wave only reads its own 16 Q-rows, and
//      per lane exactly the two bf16x8 fragments it previously re-read from
//      LDS. Drops the 8KB Qs stage -> LDS 57856 -> 50176 B -> 3 blocks/CU
//      (was 2): +50% co-resident TLP for this latency-bound kernel.
//  Issue order (pinned by "memory" fences): 6 K gload_lds -> 2 Q reg-loads
//  -> 6 V reg-loads. Manual gate vmcnt(8) retires exactly the K stages
//  (LDS-destined: compiler can't track); compiler's own dependency waits
//  cover Q before QK^T and leave V in flight until the post-softmax drain.
__launch_bounds__(256, 3)
__global__ void attn_kernel(const unsigned short* __restrict__ Qb,
                            const unsigned short* __restrict__ Kb,
                            const unsigned short* __restrict__ Vb,
                            const float* __restrict__ part,
                            float* __restrict__ out) {
  const int bid = blockIdx.x;
  const int c = bid % CDD;
  const int h = (bid / CDD) % NH;
  const int b = bid / (CDD * NH);
  const int tid = threadIdx.x;
  const int wave = tid >> 6, lane = tid & 63;
  const int col = lane & 15, quad = lane >> 4;

  __shared__ __align__(16) char smem[50176];
  unsigned short* Ks = (unsigned short*)smem;            // 192x64 (stride 64, swizzled), 24KB
  unsigned short* Ps = (unsigned short*)smem;            // 64 x stride196 bf16 (aliases Ks), 25088B
  unsigned short* Vt = (unsigned short*)(smem + 25088);  // 64 x stride196 (V transposed), 25088B

  const size_t rowQ0 = (size_t)(b * S + c * 64) * H + h * DH;

  // --- stage K (1536 slots) via global_load_lds, swizzle ^(row&7): 6 vm-ops
#pragma unroll
  for (int j = 0; j < 6; j++) {
    int s = tid + 256 * j;
    int key = s >> 3;
    int gkey = (key < 64) ? (c * 64 + key) : (576 + key);
    int gc = (s & 7) ^ (key & 7);
    gld_lds16(Kb + (size_t)(b * S + gkey) * H + h * DH + gc * 8, &Ks[s * 8]);
  }
  asm volatile("" ::: "memory");

  // --- Q fragments straight to registers (2 vm-ops/lane)
  const int rq = wave * 16 + col;
  const unsigned short* qp = Qb + rowQ0 + (size_t)rq * H;
  bf16x8 a0 = *(const bf16x8*)(qp + quad * 8);
  bf16x8 a1 = *(const bf16x8*)(qp + 32 + quad * 8);
  asm volatile("" ::: "memory");

  // --- T14: V loads issued now (regs); LDS write deferred past QK^T/softmax
  int4 uv[6];
#pragma unroll
  for (int j = 0; j < 6; j++) {
    int s = tid + 256 * j;
    int key = s >> 3;
    int f0 = (s & 7) * 8;
    int gkey = (key < 64) ? (c * 64 + key) : (576 + key);
    uv[j] = *(const int4*)(Vb + (size_t)(b * S + gkey) * H + h * DH + f0);
  }
  // counted gate: retire the 6 K stages; Q covered by compiler dep-waits;
  // the 6 V loads stay in flight.
  asm volatile("s_waitcnt vmcnt(8)" ::: "memory");
  __builtin_amdgcn_sched_barrier(0);
  __builtin_amdgcn_s_barrier();
  __builtin_amdgcn_sched_barrier(0);

  // --- QK^T: wave handles q-rows [wave*16, wave*16+16), 12 col-tiles, K=64
  f32x4 sc[12];
#pragma unroll
  for (int n = 0; n < 12; n++) sc[n] = (f32x4){0.f, 0.f, 0.f, 0.f};
#pragma unroll
  for (int n = 0; n < 12; n++) {
    const int rk = n * 16 + col;
    bf16x8 b0 = *(const bf16x8*)&Ks[rk * 64 + ((quad ^ (rk & 7)) * 8)];
    bf16x8 b1 = *(const bf16x8*)&Ks[rk * 64 + (((4 + quad) ^ (rk & 7)) * 8)];
    sc[n] = __builtin_amdgcn_mfma_f32_16x16x32_bf16(a0, b0, sc[n], 0, 0, 0);
    sc[n] = __builtin_amdgcn_mfma_f32_16x16x32_bf16(a1, b1, sc[n], 0, 0, 0);
  }

  // --- masked softmax (exact, multiplicative-mask semantics)
  float em[4], zin[4];
  {
    const float scale = 0.125f;  // 1/sqrt(64)
#pragma unroll
    for (int r = 0; r < 4; r++) {
      float mx = sc[0][r];
#pragma unroll
      for (int n = 1; n < 12; n++) mx = fmaxf(mx, sc[n][r]);
#pragma unroll
      for (int msk = 1; msk <= 8; msk <<= 1) mx = fmaxf(mx, __shfl_xor(mx, msk, 64));
      const float mrow = fmaxf(mx * scale, 0.f);
      float rs = 0.f;
#pragma unroll
      for (int n = 0; n < 12; n++) {
        float p = __expf(sc[n][r] * scale - mrow);
        sc[n][r] = p;
        rs += p;
      }
#pragma unroll
      for (int msk = 1; msk <= 8; msk <<= 1) rs += __shfl_xor(rs, msk, 64);
      const float e = __expf(-mrow);
      em[r] = e;
      zin[r] = 1.f / (rs + 576.f * e);
    }
  }
  // all waves' Ks reads done -> Ps (aliased) writes safe; drains V (vmcnt 0)
  // exactly where the transpose-writes need uv.
  __syncthreads();

  // --- P -> LDS (bf16, stride 196)
#pragma unroll
  for (int n = 0; n < 12; n++)
#pragma unroll
    for (int r = 0; r < 4; r++)
      Ps[(wave * 16 + quad * 4 + r) * 196 + n * 16 + col] = f2bf(sc[n][r]);

  // --- V transpose-write from regs: Vt[d][key], stride 196 (196%8==4)
#pragma unroll
  for (int j = 0; j < 6; j++) {
    int s = tid + 256 * j;
    int key = s >> 3;
    int f0 = (s & 7) * 8;
    union { int4 i4; unsigned short u[8]; } w;
    w.i4 = uv[j];
#pragma unroll
    for (int i = 0; i < 8; i++) Vt[(f0 + i) * 196 + key] = w.u[i];
  }
  __syncthreads();

  // --- PV (+ staged-V column sums via ones-MFMA): rows [wave*16,+16) x 64 cols
  f32x4 o[4], osum[4];
#pragma unroll
  for (int n2 = 0; n2 < 4; n2++) {
    o[n2] = (f32x4){0.f, 0.f, 0.f, 0.f};
    osum[n2] = (f32x4){0.f, 0.f, 0.f, 0.f};
  }
  bf16x8 ones;
#pragma unroll
  for (int i = 0; i < 8; i++) ones[i] = (short)0x3F80;  // bf16 1.0
#pragma unroll
  for (int ks = 0; ks < 6; ks++) {
    bf16x8 a = ld_b64x2(&Ps[(wave * 16 + col) * 196 + ks * 32 + quad * 8]);
#pragma unroll
    for (int n2 = 0; n2 < 4; n2++) {
      bf16x8 bvv = ld_b64x2(&Vt[(n2 * 16 + col) * 196 + ks * 32 + quad * 8]);
      o[n2] = __builtin_amdgcn_mfma_f32_16x16x32_bf16(a, bvv, o[n2], 0, 0, 0);
      osum[n2] = __builtin_amdgcn_mfma_f32_16x16x32_bf16(ones, bvv, osum[n2], 0, 0, 0);
    }
  }

  // --- epilogue: masked-V correction (vcorr = Vtot - staged sum), normalize
#pragma unroll
  for (int n2 = 0; n2 < 4; n2++) {
    const int d = n2 * 16 + col;
    const float vc = part[b * H + h * DH + d] - osum[n2][0];
#pragma unroll
    for (int r = 0; r < 4; r++) {
      const int m = wave * 16 + quad * 4 + r;
      const float val = (o[n2][r] + em[r] * vc) * zin[r];
      out[(size_t)(b * S + c * 64 + m) * H + h * DH + d] = val;
    }
  }
}

extern "C" void kernel_launch(void* const* d_in, const int* in_sizes, int n_in,
                              void* d_out, int out_size, void* d_ws, size_t ws_size,
                              hipStream_t stream) {
  const float* X  = (const float*)d_in[0];
  const float* Wq = (const float*)d_in[1];
  const float* bq = (const float*)d_in[2];
  const float* Wk = (const float*)d_in[3];
  const float* bk = (const float*)d_in[4];
  const float* Wv = (const float*)d_in[5];
  const float* bv = (const float*)d_in[6];
  float* out = (float*)d_out;

  char* ws = (char*)d_ws;
  // workspace layout (~75.5 MB total)
  unsigned short* Xb   = (unsigned short*)ws;                    // 12288x768 bf16
  unsigned short* Wb   = (unsigned short*)(ws + 18874368);       // 3x768x768 bf16
  unsigned short* Qb   = (unsigned short*)(ws + 22413312);       // 12288x768 bf16
  unsigned short* Kb   = (unsigned short*)(ws + 41287680);
  unsigned short* Vb   = (unsigned short*)(ws + 60162048);
  float*          part = (float*)(ws + 79036416);                // 16x768 f32 (atomic)

  hipMemsetAsync(part, 0, Bb * H * sizeof(float), stream);
  convert_all<<<2048, 256, 0, stream>>>(X, Wq, Wk, Wv, Xb, Wb);
  qkv_gemm<<<dim3(80, 6), 256, 0, stream>>>(Xb, Wb, 0, bq, bk, bv, Qb, Kb, Vb, part, out);
  qkv_gemm<<<dim3(96, 6), 256, 0, stream>>>(Xb, Wb, 1, bq, bk, bv, Qb, Kb, Vb, part, out);
  qkv_gemm<<<dim3(96, 6), 256, 0, stream>>>(Xb, Wb, 2, bq, bk, bv, Qb, Kb, Vb, part, out);
  attn_kernel<<<1920, 256, 0, stream>>>(Qb, Kb, Vb, part, out);
}

// Round 7
// 174.102 us; speedup vs baseline: 1.0593x; 1.0593x over previous
//
#include <hip/hip_runtime.h>

// Problem constants
constexpr int Bb  = 16;
constexpr int CDD = 10;
constexpr int Lc  = 64;
constexpr int T   = 128;
constexpr int H   = 768;
constexpr int NH  = 12;
constexpr int DH  = 64;    // H/NH
constexpr int S   = 768;   // CDD*Lc + T
constexpr int SQ  = 640;   // CDD*Lc
constexpr int MROWS = Bb * S;  // 12288

typedef __attribute__((ext_vector_type(8))) short bf16x8;
typedef __attribute__((ext_vector_type(4))) short bf16x4;
typedef __attribute__((ext_vector_type(4))) float f32x4;

__device__ inline unsigned short f2bf(float f) {
  unsigned u = __float_as_uint(f);
  u += 0x7fff + ((u >> 16) & 1);   // RNE
  return (unsigned short)(u >> 16);
}
__device__ inline float bf2f(unsigned short h) {
  return __uint_as_float(((unsigned)h) << 16);
}

__device__ inline void gld_lds16(const void* g, void* l) {
  __builtin_amdgcn_global_load_lds(
      (const __attribute__((address_space(1))) void*)g,
      (__attribute__((address_space(3))) void*)l, 16, 0, 0);
}

__device__ inline bf16x8 ld_b64x2(const unsigned short* p) {
  union { bf16x8 v; bf16x4 h[2]; } u;
  u.h[0] = *(const bf16x4*)p;
  u.h[1] = *(const bf16x4*)(p + 4);
  return u.v;
}

// ---------------- fp32 -> bf16 convert (X + 3 weights) + part zeroing --------
constexpr int NX4 = MROWS * H / 4;   // 2359296 float4s
constexpr int NW4 = H * H / 4;       // 147456 float4s
__global__ void convert_all(const float* __restrict__ X,
                            const float* __restrict__ Wq,
                            const float* __restrict__ Wk,
                            const float* __restrict__ Wv,
                            unsigned short* __restrict__ Xb,
                            unsigned short* __restrict__ Wb,
                            float* __restrict__ part) {
  int i = blockIdx.x * blockDim.x + threadIdx.x;
  if (i < Bb * H) part[i] = 0.f;    // fold the part-memset dispatch in here
  const int stride = gridDim.x * blockDim.x;
  const int total = NX4 + 3 * NW4;
  for (; i < total; i += stride) {
    const float* src;
    unsigned short* dst;
    int off;
    if (i < NX4) {
      src = X; dst = Xb; off = i;
    } else {
      int k = i - NX4;
      int w = k / NW4;
      off = k - w * NW4;
      src = (w == 0) ? Wq : (w == 1) ? Wk : Wv;
      dst = Wb + (size_t)w * H * H;
    }
    float4 v = ((const float4*)src)[off];
    ushort4 o;
    o.x = f2bf(v.x); o.y = f2bf(v.y); o.z = f2bf(v.z); o.w = f2bf(v.w);
    ((ushort4*)dst)[off] = o;
  }
}

// ---------------- QKV projection GEMM: Y = X * W^T + bias ----------------
// (r0 structure, proven 55 us / MfmaUtil ~30%. 128x128 tile, BK=64, 4 waves.
//  256-sq phase-interleave attempts regressed at this shape: K=768 gives only
//  12 K-tiles and 128KB LDS forces 1 block/CU -> pipeline never fills.)
// r7: single dispatch again (the r6 3-way split cost ~6us in dispatch tails),
// but with a DENSE 1D x-grid of 272 = 80 (z=0, tail-tiles remapped away) +
// 96 (z=1) + 96 (z=2) -- no dead blocks at all.
__launch_bounds__(256, 4)
__global__ void qkv_gemm(const unsigned short* __restrict__ Xb,
                         const unsigned short* __restrict__ Wb,
                         const float* __restrict__ bq, const float* __restrict__ bk,
                         const float* __restrict__ bv,
                         unsigned short* __restrict__ Qb, unsigned short* __restrict__ Kb,
                         unsigned short* __restrict__ Vb,
                         float* __restrict__ part,
                         float* __restrict__ out) {
  const int bx = blockIdx.x;
  int z, bxl, i0;
  if (bx < 80) {                     // z=0: 16 batches x 5 live row-tiles
    z = 0; bxl = bx;
    const int b6 = bx / 5, t = bx - b6 * 5;
    i0 = (b6 * 6 + t) * 128;
  } else if (bx < 176) {
    z = 1; bxl = bx - 80; i0 = bxl * 128;
  } else {
    z = 2; bxl = bx - 176; i0 = bxl * 128;
  }
  const unsigned short* W = Wb + (size_t)z * H * H;
  const float* bias = (z == 0) ? bq : (z == 1) ? bk : bv;
  unsigned short* Y = (z == 0) ? Qb : (z == 1) ? Kb : Vb;

  const int j0 = blockIdx.y * 128;
  const int tid = threadIdx.x;
  const int wave = tid >> 6, lane = tid & 63;
  const int wr = wave >> 1, wc = wave & 1;
  const int col = lane & 15, quad = lane >> 4;

  // row stride 64 elems (8 chunks of 8 bf16); chunk swizzle ^(row&7)
  __shared__ unsigned short As[128 * 64];
  __shared__ unsigned short Bs[128 * 64];

  f32x4 acc[4][4];
#pragma unroll
  for (int i = 0; i < 4; i++)
#pragma unroll
    for (int j = 0; j < 4; j++) acc[i][j] = (f32x4){0.f, 0.f, 0.f, 0.f};

  int rS[4], gcS[4];
#pragma unroll
  for (int i = 0; i < 4; i++) {
    int s = tid + 256 * i;
    rS[i] = s >> 3;
    gcS[i] = (s & 7) ^ (rS[i] & 7);
  }

  for (int kt = 0; kt < 12; kt++) {
    const int k0 = kt * 64;
#pragma unroll
    for (int i = 0; i < 4; i++)
      gld_lds16(Xb + (size_t)(i0 + rS[i]) * H + k0 + gcS[i] * 8, &As[(tid + 256 * i) * 8]);
#pragma unroll
    for (int i = 0; i < 4; i++)
      gld_lds16(W + (size_t)(j0 + rS[i]) * H + k0 + gcS[i] * 8, &Bs[(tid + 256 * i) * 8]);
    __builtin_amdgcn_s_waitcnt(0);
    __syncthreads();

#pragma unroll
    for (int h = 0; h < 2; h++) {
      bf16x8 a[4], b[4];
#pragma unroll
      for (int mt = 0; mt < 4; mt++) {
        int r = wr * 64 + mt * 16 + col;
        a[mt] = *(const bf16x8*)&As[r * 64 + (((h * 4 + quad) ^ (r & 7)) * 8)];
      }
#pragma unroll
      for (int nt = 0; nt < 4; nt++) {
        int r = wc * 64 + nt * 16 + col;
        b[nt] = *(const bf16x8*)&Bs[r * 64 + (((h * 4 + quad) ^ (r & 7)) * 8)];
      }
#pragma unroll
      for (int mt = 0; mt < 4; mt++)
#pragma unroll
        for (int nt = 0; nt < 4; nt++)
          acc[mt][nt] = __builtin_amdgcn_mfma_f32_16x16x32_bf16(a[mt], b[nt], acc[mt][nt], 0, 0, 0);
    }
    __syncthreads();
  }

  float colsum[4] = {0.f, 0.f, 0.f, 0.f};
#pragma unroll
  for (int mt = 0; mt < 4; mt++) {
#pragma unroll
    for (int nt = 0; nt < 4; nt++) {
      const int j = j0 + wc * 64 + nt * 16 + col;
      const float bj = bias[j];
#pragma unroll
      for (int r = 0; r < 4; r++) {
        const int i = i0 + wr * 64 + mt * 16 + quad * 4 + r;
        const float v = acc[mt][nt][r] + bj;
        Y[(size_t)i * H + j] = f2bf(v);
        if (z == 2) {
          colsum[nt] += v;
          int s = i - (i / S) * S;
          if (s >= SQ) out[(size_t)i * H + j] = v;  // tail rows: out = V row
        }
      }
    }
  }
  if (z == 2) {
    const int b = bxl / 6;
#pragma unroll
    for (int nt = 0; nt < 4; nt++) {
      float s = colsum[nt];
      s += __shfl_xor(s, 16, 64);
      s += __shfl_xor(s, 32, 64);
      if (quad == 0) {
        const int j = j0 + wc * 64 + nt * 16 + col;
        atomicAdd(&part[b * H + j], s);
      }
    }
  }
}

// ---------------- fused masked attention ----------------
// One block per (b, h, chunk c). 192 live keys = chunk(64) + tail(128).
// Masked keys have score exactly 0 (multiplicative mask), closed form:
//   m = max(0, max live s);  Z = sum live e^(s-m) + 576 e^-m
//   ctx = (sum live e^(s-m) v + e^-m (Vtot - sum staged v)) / Z
// r7: XCD-aware block swizzle (T1): the 10 chunk-blocks of one (b,h) share
// the same 32KB tail-K/V slice; bid=(g&7)*240+(g>>3) gives consecutive work
// units dispatch indices congruent mod 8 -> same XCD -> tail slices L2-hit.
// 1920 = 8*240 exactly (bijective).
__launch_bounds__(256, 3)
__global__ void attn_kernel(const unsigned short* __restrict__ Qb,
                            const unsigned short* __restrict__ Kb,
                            const unsigned short* __restrict__ Vb,
                            const float* __restrict__ part,
                            float* __restrict__ out) {
  const int g = blockIdx.x;
  const int bid = (g & 7) * 240 + (g >> 3);   // XCD swizzle
  const int c = bid % CDD;
  const int h = (bid / CDD) % NH;
  const int b = bid / (CDD * NH);
  const int tid = threadIdx.x;
  const int wave = tid >> 6, lane = tid & 63;
  const int col = lane & 15, quad = lane >> 4;

  __shared__ __align__(16) char smem[50176];
  unsigned short* Ks = (unsigned short*)smem;            // 192x64 (stride 64, swizzled), 24KB
  unsigned short* Ps = (unsigned short*)smem;            // 64 x stride196 bf16 (aliases Ks), 25088B
  unsigned short* Vt = (unsigned short*)(smem + 25088);  // 64 x stride196 (V transposed), 25088B

  const size_t rowQ0 = (size_t)(b * S + c * 64) * H + h * DH;

  // --- stage K (1536 slots) via global_load_lds, swizzle ^(row&7): 6 vm-ops
#pragma unroll
  for (int j = 0; j < 6; j++) {
    int s = tid + 256 * j;
    int key = s >> 3;
    int gkey = (key < 64) ? (c * 64 + key) : (576 + key);
    int gc = (s & 7) ^ (key & 7);
    gld_lds16(Kb + (size_t)(b * S + gkey) * H + h * DH + gc * 8, &Ks[s * 8]);
  }
  asm volatile("" ::: "memory");

  // --- Q fragments straight to registers (2 vm-ops/lane)
  const int rq = wave * 16 + col;
  const unsigned short* qp = Qb + rowQ0 + (size_t)rq * H;
  bf16x8 a0 = *(const bf16x8*)(qp + quad * 8);
  bf16x8 a1 = *(const bf16x8*)(qp + 32 + quad * 8);
  asm volatile("" ::: "memory");

  // --- T14: V loads issued now (regs); LDS write deferred past QK^T/softmax
  int4 uv[6];
#pragma unroll
  for (int j = 0; j < 6; j++) {
    int s = tid + 256 * j;
    int key = s >> 3;
    int f0 = (s & 7) * 8;
    int gkey = (key < 64) ? (c * 64 + key) : (576 + key);
    uv[j] = *(const int4*)(Vb + (size_t)(b * S + gkey) * H + h * DH + f0);
  }
  // counted gate: retire the 6 K stages; Q covered by compiler dep-waits;
  // the 6 V loads stay in flight.
  asm volatile("s_waitcnt vmcnt(8)" ::: "memory");
  __builtin_amdgcn_sched_barrier(0);
  __builtin_amdgcn_s_barrier();
  __builtin_amdgcn_sched_barrier(0);

  // --- QK^T: wave handles q-rows [wave*16, wave*16+16), 12 col-tiles, K=64
  f32x4 sc[12];
#pragma unroll
  for (int n = 0; n < 12; n++) sc[n] = (f32x4){0.f, 0.f, 0.f, 0.f};
#pragma unroll
  for (int n = 0; n < 12; n++) {
    const int rk = n * 16 + col;
    bf16x8 b0 = *(const bf16x8*)&Ks[rk * 64 + ((quad ^ (rk & 7)) * 8)];
    bf16x8 b1 = *(const bf16x8*)&Ks[rk * 64 + (((4 + quad) ^ (rk & 7)) * 8)];
    sc[n] = __builtin_amdgcn_mfma_f32_16x16x32_bf16(a0, b0, sc[n], 0, 0, 0);
    sc[n] = __builtin_amdgcn_mfma_f32_16x16x32_bf16(a1, b1, sc[n], 0, 0, 0);
  }

  // --- masked softmax (exact, multiplicative-mask semantics)
  float em[4], zin[4];
  {
    const float scale = 0.125f;  // 1/sqrt(64)
#pragma unroll
    for (int r = 0; r < 4; r++) {
      float mx = sc[0][r];
#pragma unroll
      for (int n = 1; n < 12; n++) mx = fmaxf(mx, sc[n][r]);
#pragma unroll
      for (int msk = 1; msk <= 8; msk <<= 1) mx = fmaxf(mx, __shfl_xor(mx, msk, 64));
      const float mrow = fmaxf(mx * scale, 0.f);
      float rs = 0.f;
#pragma unroll
      for (int n = 0; n < 12; n++) {
        float p = __expf(sc[n][r] * scale - mrow);
        sc[n][r] = p;
        rs += p;
      }
#pragma unroll
      for (int msk = 1; msk <= 8; msk <<= 1) rs += __shfl_xor(rs, msk, 64);
      const float e = __expf(-mrow);
      em[r] = e;
      zin[r] = 1.f / (rs + 576.f * e);
    }
  }
  // all waves' Ks reads done -> Ps (aliased) writes safe; drains V (vmcnt 0)
  // exactly where the transpose-writes need uv.
  __syncthreads();

  // --- P -> LDS (bf16, stride 196)
#pragma unroll
  for (int n = 0; n < 12; n++)
#pragma unroll
    for (int r = 0; r < 4; r++)
      Ps[(wave * 16 + quad * 4 + r) * 196 + n * 16 + col] = f2bf(sc[n][r]);

  // --- V transpose-write from regs: Vt[d][key], stride 196 (196%8==4)
#pragma unroll
  for (int j = 0; j < 6; j++) {
    int s = tid + 256 * j;
    int key = s >> 3;
    int f0 = (s & 7) * 8;
    union { int4 i4; unsigned short u[8]; } w;
    w.i4 = uv[j];
#pragma unroll
    for (int i = 0; i < 8; i++) Vt[(f0 + i) * 196 + key] = w.u[i];
  }
  __syncthreads();

  // --- PV (+ staged-V column sums via ones-MFMA): rows [wave*16,+16) x 64 cols
  f32x4 o[4], osum[4];
#pragma unroll
  for (int n2 = 0; n2 < 4; n2++) {
    o[n2] = (f32x4){0.f, 0.f, 0.f, 0.f};
    osum[n2] = (f32x4){0.f, 0.f, 0.f, 0.f};
  }
  bf16x8 ones;
#pragma unroll
  for (int i = 0; i < 8; i++) ones[i] = (short)0x3F80;  // bf16 1.0
#pragma unroll
  for (int ks = 0; ks < 6; ks++) {
    bf16x8 a = ld_b64x2(&Ps[(wave * 16 + col) * 196 + ks * 32 + quad * 8]);
#pragma unroll
    for (int n2 = 0; n2 < 4; n2++) {
      bf16x8 bvv = ld_b64x2(&Vt[(n2 * 16 + col) * 196 + ks * 32 + quad * 8]);
      o[n2] = __builtin_amdgcn_mfma_f32_16x16x32_bf16(a, bvv, o[n2], 0, 0, 0);
      osum[n2] = __builtin_amdgcn_mfma_f32_16x16x32_bf16(ones, bvv, osum[n2], 0, 0, 0);
    }
  }

  // --- epilogue: masked-V correction (vcorr = Vtot - staged sum), normalize
#pragma unroll
  for (int n2 = 0; n2 < 4; n2++) {
    const int d = n2 * 16 + col;
    const float vc = part[b * H + h * DH + d] - osum[n2][0];
#pragma unroll
    for (int r = 0; r < 4; r++) {
      const int m = wave * 16 + quad * 4 + r;
      const float val = (o[n2][r] + em[r] * vc) * zin[r];
      out[(size_t)(b * S + c * 64 + m) * H + h * DH + d] = val;
    }
  }
}

extern "C" void kernel_launch(void* const* d_in, const int* in_sizes, int n_in,
                              void* d_out, int out_size, void* d_ws, size_t ws_size,
                              hipStream_t stream) {
  const float* X  = (const float*)d_in[0];
  const float* Wq = (const float*)d_in[1];
  const float* bq = (const float*)d_in[2];
  const float* Wk = (const float*)d_in[3];
  const float* bk = (const float*)d_in[4];
  const float* Wv = (const float*)d_in[5];
  const float* bv = (const float*)d_in[6];
  float* out = (float*)d_out;

  char* ws = (char*)d_ws;
  // workspace layout (~75.5 MB total)
  unsigned short* Xb   = (unsigned short*)ws;                    // 12288x768 bf16
  unsigned short* Wb   = (unsigned short*)(ws + 18874368);       // 3x768x768 bf16
  unsigned short* Qb   = (unsigned short*)(ws + 22413312);       // 12288x768 bf16
  unsigned short* Kb   = (unsigned short*)(ws + 41287680);
  unsigned short* Vb   = (unsigned short*)(ws + 60162048);
  float*          part = (float*)(ws + 79036416);                // 16x768 f32 (atomic)

  convert_all<<<2048, 256, 0, stream>>>(X, Wq, Wk, Wv, Xb, Wb, part);
  qkv_gemm<<<dim3(272, 6), 256, 0, stream>>>(Xb, Wb, bq, bk, bv, Qb, Kb, Vb, part, out);
  attn_kernel<<<1920, 256, 0, stream>>>(Qb, Kb, Vb, part, out);
}

// Round 8
// 168.476 us; speedup vs baseline: 1.0947x; 1.0334x over previous
//
#include <hip/hip_runtime.h>

// Problem constants
constexpr int Bb  = 16;
constexpr int CDD = 10;
constexpr int Lc  = 64;
constexpr int T   = 128;
constexpr int H   = 768;
constexpr int NH  = 12;
constexpr int DH  = 64;    // H/NH
constexpr int S   = 768;   // CDD*Lc + T
constexpr int SQ  = 640;   // CDD*Lc
constexpr int MROWS = Bb * S;  // 12288

typedef __attribute__((ext_vector_type(8))) short bf16x8;
typedef __attribute__((ext_vector_type(4))) short bf16x4;
typedef __attribute__((ext_vector_type(4))) float f32x4;

__device__ inline unsigned short f2bf(float f) {
  unsigned u = __float_as_uint(f);
  u += 0x7fff + ((u >> 16) & 1);   // RNE
  return (unsigned short)(u >> 16);
}
__device__ inline float bf2f(unsigned short h) {
  return __uint_as_float(((unsigned)h) << 16);
}

__device__ inline void gld_lds16(const void* g, void* l) {
  __builtin_amdgcn_global_load_lds(
      (const __attribute__((address_space(1))) void*)g,
      (__attribute__((address_space(3))) void*)l, 16, 0, 0);
}

__device__ inline bf16x8 ld_b64x2(const unsigned short* p) {
  union { bf16x8 v; bf16x4 h[2]; } u;
  u.h[0] = *(const bf16x4*)p;
  u.h[1] = *(const bf16x4*)(p + 4);
  return u.v;
}

// ---------------- fp32 -> bf16 convert (X + 3 weights) + part zeroing --------
constexpr int NX4 = MROWS * H / 4;   // 2359296 float4s
constexpr int NW4 = H * H / 4;       // 147456 float4s
__global__ void convert_all(const float* __restrict__ X,
                            const float* __restrict__ Wq,
                            const float* __restrict__ Wk,
                            const float* __restrict__ Wv,
                            unsigned short* __restrict__ Xb,
                            unsigned short* __restrict__ Wb,
                            float* __restrict__ part) {
  int i = blockIdx.x * blockDim.x + threadIdx.x;
  if (i < Bb * H) part[i] = 0.f;    // fold the part-memset dispatch in here
  const int stride = gridDim.x * blockDim.x;
  const int total = NX4 + 3 * NW4;
  for (; i < total; i += stride) {
    const float* src;
    unsigned short* dst;
    int off;
    if (i < NX4) {
      src = X; dst = Xb; off = i;
    } else {
      int k = i - NX4;
      int w = k / NW4;
      off = k - w * NW4;
      src = (w == 0) ? Wq : (w == 1) ? Wk : Wv;
      dst = Wb + (size_t)w * H * H;
    }
    float4 v = ((const float4*)src)[off];
    ushort4 o;
    o.x = f2bf(v.x); o.y = f2bf(v.y); o.z = f2bf(v.z); o.w = f2bf(v.w);
    ((ushort4*)dst)[off] = o;
  }
}

// ---------------- QKV projection GEMM: Y = X * W^T + bias ----------------
// r8: back to the r5-proven grid (96,6,3) with z=blockIdx.z and early return
// for Q tail tiles. Measured twice at 55.3us / FETCH 34.9MB; the r7 1D-merged
// grid interleaved the z-ranges in dispatch order and thrashed X residency
// (57.5us / 52.5MB fetch). 128x128 tile, BK=64, 4 waves, 4 blocks/CU --
// 256-sq phase-interleave attempts (r1-r4) all regressed at this K=768 shape.
__launch_bounds__(256, 4)
__global__ void qkv_gemm(const unsigned short* __restrict__ Xb,
                         const unsigned short* __restrict__ Wb,
                         const float* __restrict__ bq, const float* __restrict__ bk,
                         const float* __restrict__ bv,
                         unsigned short* __restrict__ Qb, unsigned short* __restrict__ Kb,
                         unsigned short* __restrict__ Vb,
                         float* __restrict__ part,
                         float* __restrict__ out) {
  const int z = blockIdx.z;
  if (z == 0 && (blockIdx.x % 6) == 5) return;  // Q tail rows never consumed
  const unsigned short* W = Wb + (size_t)z * H * H;
  const float* bias = (z == 0) ? bq : (z == 1) ? bk : bv;
  unsigned short* Y = (z == 0) ? Qb : (z == 1) ? Kb : Vb;

  const int i0 = blockIdx.x * 128;
  const int j0 = blockIdx.y * 128;
  const int tid = threadIdx.x;
  const int wave = tid >> 6, lane = tid & 63;
  const int wr = wave >> 1, wc = wave & 1;
  const int col = lane & 15, quad = lane >> 4;

  // row stride 64 elems (8 chunks of 8 bf16); chunk swizzle ^(row&7)
  __shared__ unsigned short As[128 * 64];
  __shared__ unsigned short Bs[128 * 64];

  f32x4 acc[4][4];
#pragma unroll
  for (int i = 0; i < 4; i++)
#pragma unroll
    for (int j = 0; j < 4; j++) acc[i][j] = (f32x4){0.f, 0.f, 0.f, 0.f};

  int rS[4], gcS[4];
#pragma unroll
  for (int i = 0; i < 4; i++) {
    int s = tid + 256 * i;
    rS[i] = s >> 3;
    gcS[i] = (s & 7) ^ (rS[i] & 7);
  }

  for (int kt = 0; kt < 12; kt++) {
    const int k0 = kt * 64;
#pragma unroll
    for (int i = 0; i < 4; i++)
      gld_lds16(Xb + (size_t)(i0 + rS[i]) * H + k0 + gcS[i] * 8, &As[(tid + 256 * i) * 8]);
#pragma unroll
    for (int i = 0; i < 4; i++)
      gld_lds16(W + (size_t)(j0 + rS[i]) * H + k0 + gcS[i] * 8, &Bs[(tid + 256 * i) * 8]);
    __builtin_amdgcn_s_waitcnt(0);
    __syncthreads();

#pragma unroll
    for (int h = 0; h < 2; h++) {
      bf16x8 a[4], b[4];
#pragma unroll
      for (int mt = 0; mt < 4; mt++) {
        int r = wr * 64 + mt * 16 + col;
        a[mt] = *(const bf16x8*)&As[r * 64 + (((h * 4 + quad) ^ (r & 7)) * 8)];
      }
#pragma unroll
      for (int nt = 0; nt < 4; nt++) {
        int r = wc * 64 + nt * 16 + col;
        b[nt] = *(const bf16x8*)&Bs[r * 64 + (((h * 4 + quad) ^ (r & 7)) * 8)];
      }
#pragma unroll
      for (int mt = 0; mt < 4; mt++)
#pragma unroll
        for (int nt = 0; nt < 4; nt++)
          acc[mt][nt] = __builtin_amdgcn_mfma_f32_16x16x32_bf16(a[mt], b[nt], acc[mt][nt], 0, 0, 0);
    }
    __syncthreads();
  }

  float colsum[4] = {0.f, 0.f, 0.f, 0.f};
#pragma unroll
  for (int mt = 0; mt < 4; mt++) {
#pragma unroll
    for (int nt = 0; nt < 4; nt++) {
      const int j = j0 + wc * 64 + nt * 16 + col;
      const float bj = bias[j];
#pragma unroll
      for (int r = 0; r < 4; r++) {
        const int i = i0 + wr * 64 + mt * 16 + quad * 4 + r;
        const float v = acc[mt][nt][r] + bj;
        Y[(size_t)i * H + j] = f2bf(v);
        if (z == 2) {
          colsum[nt] += v;
          int s = i - (i / S) * S;
          if (s >= SQ) out[(size_t)i * H + j] = v;  // tail rows: out = V row
        }
      }
    }
  }
  if (z == 2) {
    const int b = blockIdx.x / 6;
#pragma unroll
    for (int nt = 0; nt < 4; nt++) {
      float s = colsum[nt];
      s += __shfl_xor(s, 16, 64);
      s += __shfl_xor(s, 32, 64);
      if (quad == 0) {
        const int j = j0 + wc * 64 + nt * 16 + col;
        atomicAdd(&part[b * H + j], s);
      }
    }
  }
}

// ---------------- fused masked attention ----------------
// One block per (b, h, chunk c). 192 live keys = chunk(64) + tail(128).
// Masked keys have score exactly 0 (multiplicative mask), closed form:
//   m = max(0, max live s);  Z = sum live e^(s-m) + 576 e^-m
//   ctx = (sum live e^(s-m) v + e^-m (Vtot - sum staged v)) / Z
// XCD-aware block swizzle (T1): the 10 chunk-blocks of one (b,h) share the
// same 32KB tail-K/V slice; bid=(g&7)*240+(g>>3) puts consecutive work units
// on one XCD -> tail slices L2-hit. 1920 = 8*240 exactly (bijective).
__launch_bounds__(256, 3)
__global__ void attn_kernel(const unsigned short* __restrict__ Qb,
                            const unsigned short* __restrict__ Kb,
                            const unsigned short* __restrict__ Vb,
                            const float* __restrict__ part,
                            float* __restrict__ out) {
  const int g = blockIdx.x;
  const int bid = (g & 7) * 240 + (g >> 3);   // XCD swizzle
  const int c = bid % CDD;
  const int h = (bid / CDD) % NH;
  const int b = bid / (CDD * NH);
  const int tid = threadIdx.x;
  const int wave = tid >> 6, lane = tid & 63;
  const int col = lane & 15, quad = lane >> 4;

  __shared__ __align__(16) char smem[50176];
  unsigned short* Ks = (unsigned short*)smem;            // 192x64 (stride 64, swizzled), 24KB
  unsigned short* Ps = (unsigned short*)smem;            // 64 x stride196 bf16 (aliases Ks), 25088B
  unsigned short* Vt = (unsigned short*)(smem + 25088);  // 64 x stride196 (V transposed), 25088B

  const size_t rowQ0 = (size_t)(b * S + c * 64) * H + h * DH;

  // --- stage K (1536 slots) via global_load_lds, swizzle ^(row&7): 6 vm-ops
#pragma unroll
  for (int j = 0; j < 6; j++) {
    int s = tid + 256 * j;
    int key = s >> 3;
    int gkey = (key < 64) ? (c * 64 + key) : (576 + key);
    int gc = (s & 7) ^ (key & 7);
    gld_lds16(Kb + (size_t)(b * S + gkey) * H + h * DH + gc * 8, &Ks[s * 8]);
  }
  asm volatile("" ::: "memory");

  // --- Q fragments straight to registers (2 vm-ops/lane)
  const int rq = wave * 16 + col;
  const unsigned short* qp = Qb + rowQ0 + (size_t)rq * H;
  bf16x8 a0 = *(const bf16x8*)(qp + quad * 8);
  bf16x8 a1 = *(const bf16x8*)(qp + 32 + quad * 8);
  asm volatile("" ::: "memory");

  // --- T14: V loads issued now (regs); LDS write deferred past QK^T/softmax
  int4 uv[6];
#pragma unroll
  for (int j = 0; j < 6; j++) {
    int s = tid + 256 * j;
    int key = s >> 3;
    int f0 = (s & 7) * 8;
    int gkey = (key < 64) ? (c * 64 + key) : (576 + key);
    uv[j] = *(const int4*)(Vb + (size_t)(b * S + gkey) * H + h * DH + f0);
  }
  // counted gate: retire the 6 K stages; Q covered by compiler dep-waits;
  // the 6 V loads stay in flight.
  asm volatile("s_waitcnt vmcnt(8)" ::: "memory");
  __builtin_amdgcn_sched_barrier(0);
  __builtin_amdgcn_s_barrier();
  __builtin_amdgcn_sched_barrier(0);

  // --- QK^T: wave handles q-rows [wave*16, wave*16+16), 12 col-tiles, K=64
  f32x4 sc[12];
#pragma unroll
  for (int n = 0; n < 12; n++) sc[n] = (f32x4){0.f, 0.f, 0.f, 0.f};
#pragma unroll
  for (int n = 0; n < 12; n++) {
    const int rk = n * 16 + col;
    bf16x8 b0 = *(const bf16x8*)&Ks[rk * 64 + ((quad ^ (rk & 7)) * 8)];
    bf16x8 b1 = *(const bf16x8*)&Ks[rk * 64 + (((4 + quad) ^ (rk & 7)) * 8)];
    sc[n] = __builtin_amdgcn_mfma_f32_16x16x32_bf16(a0, b0, sc[n], 0, 0, 0);
    sc[n] = __builtin_amdgcn_mfma_f32_16x16x32_bf16(a1, b1, sc[n], 0, 0, 0);
  }

  // --- masked softmax (exact, multiplicative-mask semantics)
  float em[4], zin[4];
  {
    const float scale = 0.125f;  // 1/sqrt(64)
#pragma unroll
    for (int r = 0; r < 4; r++) {
      float mx = sc[0][r];
#pragma unroll
      for (int n = 1; n < 12; n++) mx = fmaxf(mx, sc[n][r]);
#pragma unroll
      for (int msk = 1; msk <= 8; msk <<= 1) mx = fmaxf(mx, __shfl_xor(mx, msk, 64));
      const float mrow = fmaxf(mx * scale, 0.f);
      float rs = 0.f;
#pragma unroll
      for (int n = 0; n < 12; n++) {
        float p = __expf(sc[n][r] * scale - mrow);
        sc[n][r] = p;
        rs += p;
      }
#pragma unroll
      for (int msk = 1; msk <= 8; msk <<= 1) rs += __shfl_xor(rs, msk, 64);
      const float e = __expf(-mrow);
      em[r] = e;
      zin[r] = 1.f / (rs + 576.f * e);
    }
  }
  // all waves' Ks reads done -> Ps (aliased) writes safe; drains V (vmcnt 0)
  // exactly where the transpose-writes need uv.
  __syncthreads();

  // --- P -> LDS (bf16, stride 196)
#pragma unroll
  for (int n = 0; n < 12; n++)
#pragma unroll
    for (int r = 0; r < 4; r++)
      Ps[(wave * 16 + quad * 4 + r) * 196 + n * 16 + col] = f2bf(sc[n][r]);

  // --- V transpose-write from regs: Vt[d][key], stride 196 (196%8==4)
#pragma unroll
  for (int j = 0; j < 6; j++) {
    int s = tid + 256 * j;
    int key = s >> 3;
    int f0 = (s & 7) * 8;
    union { int4 i4; unsigned short u[8]; } w;
    w.i4 = uv[j];
#pragma unroll
    for (int i = 0; i < 8; i++) Vt[(f0 + i) * 196 + key] = w.u[i];
  }
  __syncthreads();

  // --- PV (+ staged-V column sums via ones-MFMA): rows [wave*16,+16) x 64 cols
  f32x4 o[4], osum[4];
#pragma unroll
  for (int n2 = 0; n2 < 4; n2++) {
    o[n2] = (f32x4){0.f, 0.f, 0.f, 0.f};
    osum[n2] = (f32x4){0.f, 0.f, 0.f, 0.f};
  }
  bf16x8 ones;
#pragma unroll
  for (int i = 0; i < 8; i++) ones[i] = (short)0x3F80;  // bf16 1.0
#pragma unroll
  for (int ks = 0; ks < 6; ks++) {
    bf16x8 a = ld_b64x2(&Ps[(wave * 16 + col) * 196 + ks * 32 + quad * 8]);
#pragma unroll
    for (int n2 = 0; n2 < 4; n2++) {
      bf16x8 bvv = ld_b64x2(&Vt[(n2 * 16 + col) * 196 + ks * 32 + quad * 8]);
      o[n2] = __builtin_amdgcn_mfma_f32_16x16x32_bf16(a, bvv, o[n2], 0, 0, 0);
      osum[n2] = __builtin_amdgcn_mfma_f32_16x16x32_bf16(ones, bvv, osum[n2], 0, 0, 0);
    }
  }

  // --- epilogue: masked-V correction (vcorr = Vtot - staged sum), normalize
#pragma unroll
  for (int n2 = 0; n2 < 4; n2++) {
    const int d = n2 * 16 + col;
    const float vc = part[b * H + h * DH + d] - osum[n2][0];
#pragma unroll
    for (int r = 0; r < 4; r++) {
      const int m = wave * 16 + quad * 4 + r;
      const float val = (o[n2][r] + em[r] * vc) * zin[r];
      out[(size_t)(b * S + c * 64 + m) * H + h * DH + d] = val;
    }
  }
}

extern "C" void kernel_launch(void* const* d_in, const int* in_sizes, int n_in,
                              void* d_out, int out_size, void* d_ws, size_t ws_size,
                              hipStream_t stream) {
  const float* X  = (const float*)d_in[0];
  const float* Wq = (const float*)d_in[1];
  const float* bq = (const float*)d_in[2];
  const float* Wk = (const float*)d_in[3];
  const float* bk = (const float*)d_in[4];
  const float* Wv = (const float*)d_in[5];
  const float* bv = (const float*)d_in[6];
  float* out = (float*)d_out;

  char* ws = (char*)d_ws;
  // workspace layout (~75.5 MB total)
  unsigned short* Xb   = (unsigned short*)ws;                    // 12288x768 bf16
  unsigned short* Wb   = (unsigned short*)(ws + 18874368);       // 3x768x768 bf16
  unsigned short* Qb   = (unsigned short*)(ws + 22413312);       // 12288x768 bf16
  unsigned short* Kb   = (unsigned short*)(ws + 41287680);
  unsigned short* Vb   = (unsigned short*)(ws + 60162048);
  float*          part = (float*)(ws + 79036416);                // 16x768 f32 (atomic)

  convert_all<<<2048, 256, 0, stream>>>(X, Wq, Wk, Wv, Xb, Wb, part);
  qkv_gemm<<<dim3(96, 6, 3), 256, 0, stream>>>(Xb, Wb, bq, bk, bv, Qb, Kb, Vb, part, out);
  attn_kernel<<<1920, 256, 0, stream>>>(Qb, Kb, Vb, part, out);
}